// Round 20
// baseline (119.944 us; speedup 1.0000x reference)
//
#include <hip/hip_runtime.h>
#include <hip/hip_fp16.h>
#include <cstdint>

typedef __attribute__((ext_vector_type(8))) short bf16x8;
typedef __attribute__((ext_vector_type(4))) float f32x4;

#if __has_builtin(__builtin_amdgcn_exp2f)
#define EXP2F(x) __builtin_amdgcn_exp2f(x)
#else
#define EXP2F(x) exp2f(x)
#endif
#if __has_builtin(__builtin_amdgcn_rcpf)
#define RCPF(x) __builtin_amdgcn_rcpf(x)
#else
#define RCPF(x) (1.0f/(x))
#endif

#define C2LOG2E 2.885390081777927f   // 2*log2(e)
#define LOG2E   1.4426950408889634f

__device__ __forceinline__ unsigned int f2bf(float f) {
    union { float f; unsigned int u; } v; v.f = f;
    return ((v.u + 0x7FFFu + ((v.u >> 16) & 1u)) >> 16);
}
__device__ __forceinline__ float bf2f(unsigned short h) {
    union { unsigned int u; float f; } v; v.u = ((unsigned int)h) << 16; return v.f;
}
__device__ __forceinline__ unsigned pack2h(float a, float b) {
    return (unsigned)__half_as_ushort(__float2half(a)) |
           ((unsigned)__half_as_ushort(__float2half(b)) << 16);
}
__device__ __forceinline__ float h_lo(unsigned u) {
    return __half2float(__ushort_as_half((unsigned short)(u & 0xffffu)));
}
__device__ __forceinline__ float h_hi(unsigned u) {
    return __half2float(__ushort_as_half((unsigned short)(u >> 16)));
}

// ---- prep: Xb bf16; XT bf16 (d-major); Wt f32 (W_ap^T); Wpab/Wpob bf16; BN consts ----
__global__ void prep_kernel(const float* __restrict__ x, const float* __restrict__ W_ap,
                            const float* __restrict__ W_pa, const float* __restrict__ W_po,
                            const float* __restrict__ b_pa, const float* __restrict__ b_po,
                            const float* __restrict__ gma, const float* __restrict__ bta,
                            const float* __restrict__ rmean, const float* __restrict__ rvar,
                            unsigned short* __restrict__ Xb, unsigned short* __restrict__ XT,
                            float* __restrict__ Wt,
                            unsigned short* __restrict__ Wpab, unsigned short* __restrict__ Wpob,
                            float* __restrict__ bnA, float* __restrict__ bnBB) {
    int t = blockIdx.x * 256 + threadIdx.x;   // 32768 threads, 8 elems each
    const float* src = x + (size_t)t * 8;
    float4 a = *(const float4*)(src);
    float4 b = *(const float4*)(src + 4);
    unsigned int p0 = f2bf(a.x) | (f2bf(a.y) << 16);
    unsigned int p1 = f2bf(a.z) | (f2bf(a.w) << 16);
    unsigned int p2 = f2bf(b.x) | (f2bf(b.y) << 16);
    unsigned int p3 = f2bf(b.z) | (f2bf(b.w) << 16);
    *(int4*)(Xb + (size_t)t * 8) = make_int4((int)p0, (int)p1, (int)p2, (int)p3);
    // XT[b][d][j]
    {
        int bb = t >> 12;
        int bj = (t >> 3) & 511;
        int d0 = (t & 7) * 8;
        unsigned short* xt = XT + (size_t)bb * (64 * 512) + bj;
        unsigned short e[8] = {(unsigned short)(p0 & 0xffff), (unsigned short)(p0 >> 16),
                               (unsigned short)(p1 & 0xffff), (unsigned short)(p1 >> 16),
                               (unsigned short)(p2 & 0xffff), (unsigned short)(p2 >> 16),
                               (unsigned short)(p3 & 0xffff), (unsigned short)(p3 >> 16)};
        #pragma unroll
        for (int k = 0; k < 8; ++k) xt[(size_t)(d0 + k) * 512] = e[k];
    }
    if (t < 64 * 64) {
        int src_i = (t & 63) * 64 + (t >> 6);   // [d][o] -> [o][d]
        Wt[t]   = W_ap[src_i];
        Wpab[t] = (unsigned short)f2bf(W_pa[src_i]);
        Wpob[t] = (unsigned short)f2bf(W_po[src_i]);
    }
    if (t < 64) {
        float A = gma[t] * rsqrtf(rvar[t] + 1e-5f);
        bnA[t]  = A;
        bnBB[t] = (b_pa[t] + b_po[t] - rmean[t]) * A + bta[t];
    }
}

// ---- A: scores, cyclic triangle (R18 coverage) + HALF-ROW PARITY SPLIT +
// <=64-unified-reg body for 8 waves/SIMD. Wave (i,h) runs s = h, h+2, ... of
// row i's cyclic window (diag s=0 -> h=0 only; exactly-once coverage kept).
// Register diet: of-paired acc (8 AGPR), n2a/cb packed as f16 pairs (16 VGPR
// total, was 32), no binit C-init. 2048 blocks = 8/CU, whole grid resident,
// 16-row lockstep preserved for mirror-store L2 coalescing.
__global__ __launch_bounds__(256, 8) void score_kernel(
    const float* __restrict__ x, const float* __restrict__ b_ap, const float* __restrict__ att_w,
    const unsigned short* __restrict__ Xb, const float* __restrict__ Wt,
    unsigned short* __restrict__ E)
{
    const int t  = threadIdx.x;
    const int l  = t & 63;
    const int w  = t >> 6;
    const int bid = blockIdx.x;
    const int b   = bid & 7;                  // XCD k <-> batch k
    const int i   = (bid >> 3) * 2 + (w >> 1);
    const int h   = w & 1;                    // parity half of the cyclic window
    const int lm = l & 15;
    const int lq = l >> 4;
    const unsigned short* __restrict__ Xg = Xb + (size_t)b * (512 * 64);
    const float* __restrict__ xi = x + ((size_t)b * 512 + i) * 64;

    // ---- A-fragments (W_i^T), pre-scaled by 2*log2(e) ----
    bf16x8 af[8];
    #pragma unroll
    for (int ks = 0; ks < 2; ++ks) {
        float4 xc0 = *(const float4*)(xi + ks * 32 + lq * 8);
        float4 xc1 = *(const float4*)(xi + ks * 32 + lq * 8 + 4);
        xc0.x *= C2LOG2E; xc0.y *= C2LOG2E; xc0.z *= C2LOG2E; xc0.w *= C2LOG2E;
        xc1.x *= C2LOG2E; xc1.y *= C2LOG2E; xc1.z *= C2LOG2E; xc1.w *= C2LOG2E;
        #pragma unroll
        for (int of = 0; of < 4; ++of) {
            const float* wr = Wt + (of * 16 + lm) * 64 + ks * 32 + lq * 8;
            float4 w0 = *(const float4*)(wr);
            float4 w1 = *(const float4*)(wr + 4);
            unsigned int p0 = f2bf(w0.x * xc0.x) | (f2bf(w0.y * xc0.y) << 16);
            unsigned int p1 = f2bf(w0.z * xc0.z) | (f2bf(w0.w * xc0.w) << 16);
            unsigned int p2 = f2bf(w1.x * xc1.x) | (f2bf(w1.y * xc1.y) << 16);
            unsigned int p3 = f2bf(w1.z * xc1.z) | (f2bf(w1.w * xc1.w) << 16);
            int4 pk = make_int4((int)p0, (int)p1, (int)p2, (int)p3);
            af[of * 2 + ks] = *reinterpret_cast<bf16x8*>(&pk);
        }
    }

    // ---- packed per-lane o-consts (f16 pairs): n2a = -2a, cb = C2LOG2E*b ----
    unsigned n2ap[8], cbp[8];
    float asum = 0.f, aabs = 0.f;
    #pragma unroll
    for (int of = 0; of < 4; ++of) {
        #pragma unroll
        for (int rp = 0; rp < 2; ++rp) {
            int o = of * 16 + lq * 4 + rp * 2;
            float a0 = att_w[o], a1 = att_w[o + 1];
            n2ap[of * 2 + rp] = pack2h(-2.f * a0, -2.f * a1);
            cbp[of * 2 + rp]  = pack2h(C2LOG2E * b_ap[o], C2LOG2E * b_ap[o + 1]);
            asum += a0 + a1;
            aabs += fabsf(a0) + fabsf(a1);
        }
    }
    asum += __shfl_xor(asum, 16); asum += __shfl_xor(asum, 32);
    aabs += __shfl_xor(aabs, 16); aabs += __shfl_xor(aabs, 32);
    const float coff = (asum - aabs) * LOG2E;  // e_j = exp2(part*lg2e + coff)

    const int it0 = i >> 4;
    const int smax = (it0 < 16) ? 17 : 16;
    unsigned short* __restrict__ Erow = E + ((size_t)b * 512 + i) * 512;
    unsigned short* __restrict__ Ecol = E + (size_t)b * (512 * 512) + i;
    const unsigned short* xrow = Xg + lm * 64 + lq * 8;

    for (int s = h; s < smax; s += 2) {
        const int jt = (it0 + s) & 31;
        bf16x8 b0 = *(const bf16x8*)(xrow + jt * 1024);
        bf16x8 b1 = *(const bf16x8*)(xrow + jt * 1024 + 32);
        float part = 0.f;
        #pragma unroll
        for (int ofp = 0; ofp < 2; ++ofp) {
            f32x4 acc0 = (f32x4){0.f, 0.f, 0.f, 0.f};
            f32x4 acc1 = (f32x4){0.f, 0.f, 0.f, 0.f};
            acc0 = __builtin_amdgcn_mfma_f32_16x16x32_bf16(af[(ofp * 2 + 0) * 2 + 0], b0, acc0, 0, 0, 0);
            acc1 = __builtin_amdgcn_mfma_f32_16x16x32_bf16(af[(ofp * 2 + 1) * 2 + 0], b0, acc1, 0, 0, 0);
            acc0 = __builtin_amdgcn_mfma_f32_16x16x32_bf16(af[(ofp * 2 + 0) * 2 + 1], b1, acc0, 0, 0, 0);
            acc1 = __builtin_amdgcn_mfma_f32_16x16x32_bf16(af[(ofp * 2 + 1) * 2 + 1], b1, acc1, 0, 0, 0);
            float q0 = 0.f, q1 = 0.f;
            #pragma unroll
            for (int rp = 0; rp < 2; ++rp) {
                unsigned uc0 = cbp[(ofp * 2 + 0) * 2 + rp];
                unsigned uc1 = cbp[(ofp * 2 + 1) * 2 + rp];
                unsigned un0 = n2ap[(ofp * 2 + 0) * 2 + rp];
                unsigned un1 = n2ap[(ofp * 2 + 1) * 2 + rp];
                float e00 = EXP2F(acc0[rp * 2]     + h_lo(uc0));
                float e01 = EXP2F(acc0[rp * 2 + 1] + h_hi(uc0));
                float e10 = EXP2F(acc1[rp * 2]     + h_lo(uc1));
                float e11 = EXP2F(acc1[rp * 2 + 1] + h_hi(uc1));
                q0 = fmaf(h_lo(un0), RCPF(1.f + e00), q0);
                q0 = fmaf(h_hi(un0), RCPF(1.f + e01), q0);
                q1 = fmaf(h_lo(un1), RCPF(1.f + e10), q1);
                q1 = fmaf(h_hi(un1), RCPF(1.f + e11), q1);
            }
            part += q0 + q1;
        }
        part += __shfl_xor(part, 16);
        part += __shfl_xor(part, 32);          // all lanes: full (s - asum) for j=jt*16+lm
        float ee = EXP2F(fmaf(part, LOG2E, coff));
        unsigned short eb = (unsigned short)f2bf(ee);
        if (l < 16) {
            int j = jt * 16 + l;
            Erow[j] = eb;                                   // direct, always
            if (s != 0) Ecol[(size_t)j * 512] = eb;         // mirror (diag: none)
        }
    }
}

// ---- B: agg GEMM (E @ X) + projections + BN + SELU, all MFMA. ----
__global__ __launch_bounds__(256, 4) void agg_kernel(
    const unsigned short* __restrict__ Xb, const unsigned short* __restrict__ XT,
    const unsigned short* __restrict__ E,
    const unsigned short* __restrict__ Wpab, const unsigned short* __restrict__ Wpob,
    const float* __restrict__ bnA, const float* __restrict__ bnBB,
    float* __restrict__ out)
{
    __shared__ float sInv[16];
    __shared__ unsigned short pA[16][72];   // bf16 unnormalized agg, +8 pad

    const int t  = threadIdx.x;
    const int l  = t & 63;
    const int w  = t >> 6;
    const int bid = blockIdx.x;
    const int b   = bid & 7;                  // same XCD<->batch map: E, XT L2-hot
    const int i0  = (bid >> 3) * 16;
    const int lm = l & 15;
    const int lq = l >> 4;

    // ---- GEMM 1: acc[i-off][d-off] = sum_j E[i][j] * X[j][d], d-tile = w ----
    const unsigned short* Erow  = E  + ((size_t)b * 512 + i0 + lm) * 512 + lq * 8;
    const unsigned short* xtrow = XT + (size_t)b * (64 * 512) + (w * 16 + lm) * 512 + lq * 8;
    f32x4 acc = (f32x4){0.f, 0.f, 0.f, 0.f};
    float den = 0.f;
    #pragma unroll
    for (int jc = 0; jc < 16; ++jc) {
        bf16x8 ae = *(const bf16x8*)(Erow + jc * 32);
        bf16x8 bx = *(const bf16x8*)(xtrow + jc * 32);
        acc = __builtin_amdgcn_mfma_f32_16x16x32_bf16(ae, bx, acc, 0, 0, 0);
        if (w == 0) {
            #pragma unroll
            for (int e = 0; e < 8; ++e) den += bf2f((unsigned short)ae[e]);
        }
    }
    if (w == 0) {
        den += __shfl_xor(den, 16);
        den += __shfl_xor(den, 32);
        if (l < 16) sInv[l] = RCPF(den);
    }
    #pragma unroll
    for (int r = 0; r < 4; ++r)
        pA[lq * 4 + r][w * 16 + lm] = (unsigned short)f2bf(acc[r]);
    __syncthreads();

    // ---- GEMM 2: h = inv[i] * (aggU @ W_pa) + (x @ W_po); o-tile = w ----
    bf16x8 af2[2], afx[2], bwa[2], bwo[2];
    #pragma unroll
    for (int kc = 0; kc < 2; ++kc) {
        af2[kc] = *(const bf16x8*)(&pA[lm][kc * 32 + lq * 8]);
        afx[kc] = *(const bf16x8*)(Xb + ((size_t)b * 512 + i0 + lm) * 64 + kc * 32 + lq * 8);
        bwa[kc] = *(const bf16x8*)(Wpab + (w * 16 + lm) * 64 + kc * 32 + lq * 8);
        bwo[kc] = *(const bf16x8*)(Wpob + (w * 16 + lm) * 64 + kc * 32 + lq * 8);
    }
    f32x4 a2a = (f32x4){0.f, 0.f, 0.f, 0.f};
    f32x4 a2x = (f32x4){0.f, 0.f, 0.f, 0.f};
    a2a = __builtin_amdgcn_mfma_f32_16x16x32_bf16(af2[0], bwa[0], a2a, 0, 0, 0);
    a2x = __builtin_amdgcn_mfma_f32_16x16x32_bf16(afx[0], bwo[0], a2x, 0, 0, 0);
    a2a = __builtin_amdgcn_mfma_f32_16x16x32_bf16(af2[1], bwa[1], a2a, 0, 0, 0);
    a2x = __builtin_amdgcn_mfma_f32_16x16x32_bf16(afx[1], bwo[1], a2x, 0, 0, 0);

    // ---- epilogue: BN (biases folded) + SELU ----
    const int o = w * 16 + lm;
    const float A  = bnA[o];
    const float BB = bnBB[o];
    const float alpha = 1.6732632423543772f, scale = 1.0507009873554805f;
    #pragma unroll
    for (int r = 0; r < 4; ++r) {
        int i = i0 + lq * 4 + r;
        float hv = fmaf(sInv[lq * 4 + r], a2a[r], a2x[r]);
        hv = fmaf(hv, A, BB);
        float neg = alpha * (EXP2F(hv * LOG2E) - 1.0f);
        out[((size_t)b * 512 + i) * 64 + o] = scale * (hv > 0.f ? hv : neg);
    }
}

extern "C" void kernel_launch(void* const* d_in, const int* in_sizes, int n_in,
                              void* d_out, int out_size, void* d_ws, size_t ws_size,
                              hipStream_t stream) {
    const float* x     = (const float*)d_in[0];
    const float* W_ap  = (const float*)d_in[1];
    const float* b_ap  = (const float*)d_in[2];
    const float* att_w = (const float*)d_in[3];
    const float* W_pa  = (const float*)d_in[4];
    const float* b_pa  = (const float*)d_in[5];
    const float* W_po  = (const float*)d_in[6];
    const float* b_po  = (const float*)d_in[7];
    const float* gma   = (const float*)d_in[8];
    const float* bta   = (const float*)d_in[9];
    const float* rmean = (const float*)d_in[10];
    const float* rvar  = (const float*)d_in[11];

    char* ws = (char*)d_ws;
    unsigned short* Xb   = (unsigned short*)ws;                 // 512 KB bf16 X
    unsigned short* XT   = (unsigned short*)(ws + 512 * 1024);  // 512 KB bf16 X^T (d-major)
    float* Wt            = (float*)(ws + 1024 * 1024);          // 16 KB W_ap^T f32
    unsigned short* Wpab = (unsigned short*)(ws + 1040 * 1024); // 8 KB W_pa^T bf16
    unsigned short* Wpob = (unsigned short*)(ws + 1048 * 1024); // 8 KB W_po^T bf16
    float* bnA           = (float*)(ws + 1056 * 1024);          // 256 B
    float* bnBB          = (float*)(ws + 1057 * 1024);          // 256 B
    unsigned short* E    = (unsigned short*)(ws + 1088 * 1024); // 4 MB bf16 E[b][i][j]
    float* out           = (float*)d_out;

    prep_kernel<<<128, 256, 0, stream>>>(x, W_ap, W_pa, W_po, b_pa, b_po, gma, bta,
                                         rmean, rvar, Xb, XT, Wt, Wpab, Wpob, bnA, bnBB);
    score_kernel<<<2048, 256, 0, stream>>>(x, b_ap, att_w, Xb, Wt, E);
    agg_kernel<<<256, 256, 0, stream>>>(Xb, XT, E, Wpab, Wpob, bnA, bnBB, out);
}

// Round 21
// 51.439 us; speedup vs baseline: 2.3318x; 2.3318x over previous
//
#include <hip/hip_runtime.h>
#include <cstdint>

typedef __attribute__((ext_vector_type(8))) short bf16x8;
typedef __attribute__((ext_vector_type(4))) float f32x4;

#if __has_builtin(__builtin_amdgcn_exp2f)
#define EXP2F(x) __builtin_amdgcn_exp2f(x)
#else
#define EXP2F(x) exp2f(x)
#endif
#if __has_builtin(__builtin_amdgcn_rcpf)
#define RCPF(x) __builtin_amdgcn_rcpf(x)
#else
#define RCPF(x) (1.0f/(x))
#endif

#define C2LOG2E 2.885390081777927f   // 2*log2(e)
#define LOG2E   1.4426950408889634f

__device__ __forceinline__ unsigned int f2bf(float f) {
    union { float f; unsigned int u; } v; v.f = f;
    return ((v.u + 0x7FFFu + ((v.u >> 16) & 1u)) >> 16);
}
__device__ __forceinline__ float bf2f(unsigned short h) {
    union { unsigned int u; float f; } v; v.u = ((unsigned int)h) << 16; return v.f;
}

// ---- prep: Xb bf16; XT bf16 (d-major); Wt f32 (W_ap^T); Wpab/Wpob bf16; BN consts ----
__global__ void prep_kernel(const float* __restrict__ x, const float* __restrict__ W_ap,
                            const float* __restrict__ W_pa, const float* __restrict__ W_po,
                            const float* __restrict__ b_pa, const float* __restrict__ b_po,
                            const float* __restrict__ gma, const float* __restrict__ bta,
                            const float* __restrict__ rmean, const float* __restrict__ rvar,
                            unsigned short* __restrict__ Xb, unsigned short* __restrict__ XT,
                            float* __restrict__ Wt,
                            unsigned short* __restrict__ Wpab, unsigned short* __restrict__ Wpob,
                            float* __restrict__ bnA, float* __restrict__ bnBB) {
    int t = blockIdx.x * 256 + threadIdx.x;   // 32768 threads, 8 elems each
    const float* src = x + (size_t)t * 8;
    float4 a = *(const float4*)(src);
    float4 b = *(const float4*)(src + 4);
    unsigned int p0 = f2bf(a.x) | (f2bf(a.y) << 16);
    unsigned int p1 = f2bf(a.z) | (f2bf(a.w) << 16);
    unsigned int p2 = f2bf(b.x) | (f2bf(b.y) << 16);
    unsigned int p3 = f2bf(b.z) | (f2bf(b.w) << 16);
    *(int4*)(Xb + (size_t)t * 8) = make_int4((int)p0, (int)p1, (int)p2, (int)p3);
    // XT[b][d][j]
    {
        int bb = t >> 12;
        int bj = (t >> 3) & 511;
        int d0 = (t & 7) * 8;
        unsigned short* xt = XT + (size_t)bb * (64 * 512) + bj;
        unsigned short e[8] = {(unsigned short)(p0 & 0xffff), (unsigned short)(p0 >> 16),
                               (unsigned short)(p1 & 0xffff), (unsigned short)(p1 >> 16),
                               (unsigned short)(p2 & 0xffff), (unsigned short)(p2 >> 16),
                               (unsigned short)(p3 & 0xffff), (unsigned short)(p3 >> 16)};
        #pragma unroll
        for (int k = 0; k < 8; ++k) xt[(size_t)(d0 + k) * 512] = e[k];
    }
    if (t < 64 * 64) {
        int src_i = (t & 63) * 64 + (t >> 6);   // [d][o] -> [o][d]
        Wt[t]   = W_ap[src_i];
        Wpab[t] = (unsigned short)f2bf(W_pa[src_i]);
        Wpob[t] = (unsigned short)f2bf(W_po[src_i]);
    }
    if (t < 64) {
        float A = gma[t] * rsqrtf(rvar[t] + 1e-5f);
        bnA[t]  = A;
        bnBB[t] = (b_pa[t] + b_po[t] - rmean[t]) * A + bta[t];
    }
}

// 8 MFMAs for one 16-j tile, bias pre-folded via binit C-init
#define MFMA_TILE(A0,A1,A2,A3, B0,B1)                                              \
    A0 = __builtin_amdgcn_mfma_f32_16x16x32_bf16(af[0], B0, binit[0], 0, 0, 0);    \
    A1 = __builtin_amdgcn_mfma_f32_16x16x32_bf16(af[2], B0, binit[1], 0, 0, 0);    \
    A2 = __builtin_amdgcn_mfma_f32_16x16x32_bf16(af[4], B0, binit[2], 0, 0, 0);    \
    A3 = __builtin_amdgcn_mfma_f32_16x16x32_bf16(af[6], B0, binit[3], 0, 0, 0);    \
    A0 = __builtin_amdgcn_mfma_f32_16x16x32_bf16(af[1], B1, A0, 0, 0, 0);          \
    A1 = __builtin_amdgcn_mfma_f32_16x16x32_bf16(af[3], B1, A1, 0, 0, 0);          \
    A2 = __builtin_amdgcn_mfma_f32_16x16x32_bf16(af[5], B1, A2, 0, 0, 0);          \
    A3 = __builtin_amdgcn_mfma_f32_16x16x32_bf16(af[7], B1, A3, 0, 0, 0);

// flattened trans chains + reduce + e-store (R18's proven body)
#define SCORE_TILE(A0,A1,A2,A3, JT, MIRROR) {                                      \
    float ex[16], tt[16];                                                          \
    _Pragma("unroll")                                                              \
    for (int r = 0; r < 4; ++r) {                                                  \
        ex[r]      = EXP2F(A0[r]);                                                 \
        ex[4 + r]  = EXP2F(A1[r]);                                                 \
        ex[8 + r]  = EXP2F(A2[r]);                                                 \
        ex[12 + r] = EXP2F(A3[r]);                                                 \
    }                                                                              \
    _Pragma("unroll")                                                              \
    for (int k = 0; k < 16; ++k) tt[k] = RCPF(1.f + ex[k]);                        \
    float q0 = 0.f, q1 = 0.f, q2 = 0.f, q3 = 0.f;                                  \
    _Pragma("unroll")                                                              \
    for (int r = 0; r < 4; ++r) {                                                  \
        q0 = fmaf(n2a[r],      tt[r],      q0);                                    \
        q1 = fmaf(n2a[4 + r],  tt[4 + r],  q1);                                    \
        q2 = fmaf(n2a[8 + r],  tt[8 + r],  q2);                                    \
        q3 = fmaf(n2a[12 + r], tt[12 + r], q3);                                    \
    }                                                                              \
    float ss = (q0 + q1) + (q2 + q3);                                              \
    ss += __shfl_xor(ss, 16);                                                      \
    ss += __shfl_xor(ss, 32);                                                      \
    float ee = EXP2F(fmaf(ss, LOG2E, coff));                                       \
    unsigned short eb = (unsigned short)f2bf(ee);                                  \
    if (l < 16) {                                                                  \
        int j = (JT) * 16 + l;                                                     \
        Erow[j] = eb;                                                              \
        if (MIRROR) Ecol[(size_t)j * 512] = eb;                                    \
    }                                                                              \
}

// ---- A: scores, cyclic triangle (R18 coverage), SOFTWARE-PIPELINED PAIRS.
// Diag tile (s=0, no mirror) peeled; mirrored window = 16 tiles (it0<16) or
// 15+tail (it0>=16), processed 2-at-a-time with named acc sets A/B:
//   MFMA A; MFMA B; preload next pair; SCORE(A); SCORE(B)
// -> B's MFMA latency + next-pair L2 loads hide under ~600cyc of SCORE work.
// (R17's pragma-unroll failed: compiler reused temps and serialized.)
// Same 4-waves/SIMD point (~110-120 regs < 128); 16-row lockstep preserved.
__global__ __launch_bounds__(256, 4) void score_kernel(
    const float* __restrict__ x, const float* __restrict__ b_ap, const float* __restrict__ att_w,
    const unsigned short* __restrict__ Xb, const float* __restrict__ Wt,
    unsigned short* __restrict__ E)
{
    const int t  = threadIdx.x;
    const int l  = t & 63;
    const int w  = t >> 6;
    const int bid = blockIdx.x;
    const int b   = bid & 7;                  // XCD k <-> batch k
    const int i   = (bid >> 3) * 4 + w;
    const int lm = l & 15;
    const int lq = l >> 4;
    const unsigned short* __restrict__ Xg = Xb + (size_t)b * (512 * 64);
    const float* __restrict__ xi = x + ((size_t)b * 512 + i) * 64;

    // ---- A-fragments (W_i^T), pre-scaled by 2*log2(e) ----
    bf16x8 af[8];
    #pragma unroll
    for (int ks = 0; ks < 2; ++ks) {
        float4 xc0 = *(const float4*)(xi + ks * 32 + lq * 8);
        float4 xc1 = *(const float4*)(xi + ks * 32 + lq * 8 + 4);
        xc0.x *= C2LOG2E; xc0.y *= C2LOG2E; xc0.z *= C2LOG2E; xc0.w *= C2LOG2E;
        xc1.x *= C2LOG2E; xc1.y *= C2LOG2E; xc1.z *= C2LOG2E; xc1.w *= C2LOG2E;
        #pragma unroll
        for (int of = 0; of < 4; ++of) {
            const float* wr = Wt + (of * 16 + lm) * 64 + ks * 32 + lq * 8;
            float4 w0 = *(const float4*)(wr);
            float4 w1 = *(const float4*)(wr + 4);
            unsigned int p0 = f2bf(w0.x * xc0.x) | (f2bf(w0.y * xc0.y) << 16);
            unsigned int p1 = f2bf(w0.z * xc0.z) | (f2bf(w0.w * xc0.w) << 16);
            unsigned int p2 = f2bf(w1.x * xc1.x) | (f2bf(w1.y * xc1.y) << 16);
            unsigned int p3 = f2bf(w1.z * xc1.z) | (f2bf(w1.w * xc1.w) << 16);
            int4 pk = make_int4((int)p0, (int)p1, (int)p2, (int)p3);
            af[of * 2 + ks] = *reinterpret_cast<bf16x8*>(&pk);
        }
    }

    // ---- per-lane o-consts; bias folded into MFMA C-init ----
    float n2a[16];
    f32x4 binit[4];
    float asum = 0.f, aabs = 0.f;
    #pragma unroll
    for (int of = 0; of < 4; ++of) {
        #pragma unroll
        for (int r = 0; r < 4; ++r) {
            int o = of * 16 + lq * 4 + r;
            float a = att_w[o];
            n2a[of * 4 + r] = -2.f * a;
            binit[of][r]    = C2LOG2E * b_ap[o];
            asum += a;
            aabs += fabsf(a);
        }
    }
    asum += __shfl_xor(asum, 16); asum += __shfl_xor(asum, 32);
    aabs += __shfl_xor(aabs, 16); aabs += __shfl_xor(aabs, 32);
    const float coff = (asum - aabs) * LOG2E;  // e_j = exp2(ss*lg2e + coff)

    const int it0 = i >> 4;
    unsigned short* __restrict__ Erow = E + ((size_t)b * 512 + i) * 512;
    unsigned short* __restrict__ Ecol = E + (size_t)b * (512 * 512) + i;
    const unsigned short* xrow = Xg + lm * 64 + lq * 8;

    // ---- prologue: diag tile (no mirror) + preload first mirrored pair ----
    bf16x8 pb0, pb1, pc0, pc1;
    {
        bf16x8 d0 = *(const bf16x8*)(xrow + it0 * 1024);
        bf16x8 d1 = *(const bf16x8*)(xrow + it0 * 1024 + 32);
        f32x4 A0, A1, A2, A3;
        MFMA_TILE(A0, A1, A2, A3, d0, d1);
        int jt1 = (it0 + 1) & 31, jt2 = (it0 + 2) & 31;
        pb0 = *(const bf16x8*)(xrow + jt1 * 1024);
        pb1 = *(const bf16x8*)(xrow + jt1 * 1024 + 32);
        pc0 = *(const bf16x8*)(xrow + jt2 * 1024);
        pc1 = *(const bf16x8*)(xrow + jt2 * 1024 + 32);
        SCORE_TILE(A0, A1, A2, A3, it0, false);
    }

    const int nMir  = (it0 < 16) ? 16 : 15;   // mirrored tiles after the diag
    const int nPair = nMir >> 1;              // 8 or 7
    int s = 1;
    #pragma unroll 1
    for (int p = 0; p < nPair; ++p, s += 2) {
        const int jtA = (it0 + s) & 31;
        const int jtB = (it0 + s + 1) & 31;
        f32x4 A0, A1, A2, A3, B0, B1, B2, B3;
        MFMA_TILE(A0, A1, A2, A3, pb0, pb1);
        MFMA_TILE(B0, B1, B2, B3, pc0, pc1);
        if (p + 1 < nPair) {                   // preload next pair (issue only)
            int jt3 = (it0 + s + 2) & 31, jt4 = (it0 + s + 3) & 31;
            pb0 = *(const bf16x8*)(xrow + jt3 * 1024);
            pb1 = *(const bf16x8*)(xrow + jt3 * 1024 + 32);
            pc0 = *(const bf16x8*)(xrow + jt4 * 1024);
            pc1 = *(const bf16x8*)(xrow + jt4 * 1024 + 32);
        }
        SCORE_TILE(A0, A1, A2, A3, jtA, true);
        SCORE_TILE(B0, B1, B2, B3, jtB, true);
    }
    if (nMir & 1) {                            // tail single (it0>=16 only)
        const int jt = (it0 + s) & 31;
        bf16x8 t0 = *(const bf16x8*)(xrow + jt * 1024);
        bf16x8 t1 = *(const bf16x8*)(xrow + jt * 1024 + 32);
        f32x4 A0, A1, A2, A3;
        MFMA_TILE(A0, A1, A2, A3, t0, t1);
        SCORE_TILE(A0, A1, A2, A3, jt, true);
    }
}

// ---- B: agg GEMM (E @ X) + projections + BN + SELU, all MFMA. ----
__global__ __launch_bounds__(256, 4) void agg_kernel(
    const unsigned short* __restrict__ Xb, const unsigned short* __restrict__ XT,
    const unsigned short* __restrict__ E,
    const unsigned short* __restrict__ Wpab, const unsigned short* __restrict__ Wpob,
    const float* __restrict__ bnA, const float* __restrict__ bnBB,
    float* __restrict__ out)
{
    __shared__ float sInv[16];
    __shared__ unsigned short pA[16][72];   // bf16 unnormalized agg, +8 pad

    const int t  = threadIdx.x;
    const int l  = t & 63;
    const int w  = t >> 6;
    const int bid = blockIdx.x;
    const int b   = bid & 7;                  // same XCD<->batch map: E, XT L2-hot
    const int i0  = (bid >> 3) * 16;
    const int lm = l & 15;
    const int lq = l >> 4;

    // ---- GEMM 1: acc[i-off][d-off] = sum_j E[i][j] * X[j][d], d-tile = w ----
    const unsigned short* Erow  = E  + ((size_t)b * 512 + i0 + lm) * 512 + lq * 8;
    const unsigned short* xtrow = XT + (size_t)b * (64 * 512) + (w * 16 + lm) * 512 + lq * 8;
    f32x4 acc = (f32x4){0.f, 0.f, 0.f, 0.f};
    float den = 0.f;
    #pragma unroll
    for (int jc = 0; jc < 16; ++jc) {
        bf16x8 ae = *(const bf16x8*)(Erow + jc * 32);
        bf16x8 bx = *(const bf16x8*)(xtrow + jc * 32);
        acc = __builtin_amdgcn_mfma_f32_16x16x32_bf16(ae, bx, acc, 0, 0, 0);
        if (w == 0) {
            #pragma unroll
            for (int e = 0; e < 8; ++e) den += bf2f((unsigned short)ae[e]);
        }
    }
    if (w == 0) {
        den += __shfl_xor(den, 16);
        den += __shfl_xor(den, 32);
        if (l < 16) sInv[l] = RCPF(den);
    }
    #pragma unroll
    for (int r = 0; r < 4; ++r)
        pA[lq * 4 + r][w * 16 + lm] = (unsigned short)f2bf(acc[r]);
    __syncthreads();

    // ---- GEMM 2: h = inv[i] * (aggU @ W_pa) + (x @ W_po); o-tile = w ----
    bf16x8 af2[2], afx[2], bwa[2], bwo[2];
    #pragma unroll
    for (int kc = 0; kc < 2; ++kc) {
        af2[kc] = *(const bf16x8*)(&pA[lm][kc * 32 + lq * 8]);
        afx[kc] = *(const bf16x8*)(Xb + ((size_t)b * 512 + i0 + lm) * 64 + kc * 32 + lq * 8);
        bwa[kc] = *(const bf16x8*)(Wpab + (w * 16 + lm) * 64 + kc * 32 + lq * 8);
        bwo[kc] = *(const bf16x8*)(Wpob + (w * 16 + lm) * 64 + kc * 32 + lq * 8);
    }
    f32x4 a2a = (f32x4){0.f, 0.f, 0.f, 0.f};
    f32x4 a2x = (f32x4){0.f, 0.f, 0.f, 0.f};
    a2a = __builtin_amdgcn_mfma_f32_16x16x32_bf16(af2[0], bwa[0], a2a, 0, 0, 0);
    a2x = __builtin_amdgcn_mfma_f32_16x16x32_bf16(afx[0], bwo[0], a2x, 0, 0, 0);
    a2a = __builtin_amdgcn_mfma_f32_16x16x32_bf16(af2[1], bwa[1], a2a, 0, 0, 0);
    a2x = __builtin_amdgcn_mfma_f32_16x16x32_bf16(afx[1], bwo[1], a2x, 0, 0, 0);

    // ---- epilogue: BN (biases folded) + SELU ----
    const int o = w * 16 + lm;
    const float A  = bnA[o];
    const float BB = bnBB[o];
    const float alpha = 1.6732632423543772f, scale = 1.0507009873554805f;
    #pragma unroll
    for (int r = 0; r < 4; ++r) {
        int i = i0 + lq * 4 + r;
        float hv = fmaf(sInv[lq * 4 + r], a2a[r], a2x[r]);
        hv = fmaf(hv, A, BB);
        float neg = alpha * (EXP2F(hv * LOG2E) - 1.0f);
        out[((size_t)b * 512 + i) * 64 + o] = scale * (hv > 0.f ? hv : neg);
    }
}

extern "C" void kernel_launch(void* const* d_in, const int* in_sizes, int n_in,
                              void* d_out, int out_size, void* d_ws, size_t ws_size,
                              hipStream_t stream) {
    const float* x     = (const float*)d_in[0];
    const float* W_ap  = (const float*)d_in[1];
    const float* b_ap  = (const float*)d_in[2];
    const float* att_w = (const float*)d_in[3];
    const float* W_pa  = (const float*)d_in[4];
    const float* b_pa  = (const float*)d_in[5];
    const float* W_po  = (const float*)d_in[6];
    const float* b_po  = (const float*)d_in[7];
    const float* gma   = (const float*)d_in[8];
    const float* bta   = (const float*)d_in[9];
    const float* rmean = (const float*)d_in[10];
    const float* rvar  = (const float*)d_in[11];

    char* ws = (char*)d_ws;
    unsigned short* Xb   = (unsigned short*)ws;                 // 512 KB bf16 X
    unsigned short* XT   = (unsigned short*)(ws + 512 * 1024);  // 512 KB bf16 X^T (d-major)
    float* Wt            = (float*)(ws + 1024 * 1024);          // 16 KB W_ap^T f32
    unsigned short* Wpab = (unsigned short*)(ws + 1040 * 1024); // 8 KB W_pa^T bf16
    unsigned short* Wpob = (unsigned short*)(ws + 1048 * 1024); // 8 KB W_po^T bf16
    float* bnA           = (float*)(ws + 1056 * 1024);          // 256 B
    float* bnBB          = (float*)(ws + 1057 * 1024);          // 256 B
    unsigned short* E    = (unsigned short*)(ws + 1088 * 1024); // 4 MB bf16 E[b][i][j]
    float* out           = (float*)d_out;

    prep_kernel<<<128, 256, 0, stream>>>(x, W_ap, W_pa, W_po, b_pa, b_po, gma, bta,
                                         rmean, rvar, Xb, XT, Wt, Wpab, Wpob, bnA, bnBB);
    score_kernel<<<1024, 256, 0, stream>>>(x, b_ap, att_w, Xb, Wt, E);
    agg_kernel<<<256, 256, 0, stream>>>(Xb, XT, E, Wpab, Wpob, bnA, bnBB, out);
}